// Round 9
// baseline (455.184 us; speedup 1.0000x reference)
//
#include <hip/hip_runtime.h>
#include <hip/hip_bf16.h>

// GraphPropLayer on MI355X — round 19: per-node bins, sort-free k_aggf.
//  r18 lesson: k_aggf's ~25-30us setup (histogram/scan/scatter) was the
//  parasite; work-stealing serialized it (82->125us regression). Fix:
//  eliminate it. k_bins now appends records directly to per-node,
//  per-direction lists (binbuf[g*64+slot], slot=atomicAdd(&deg[g],1),
//  cap 64 >> Poisson(16) tail). k_aggf: no LDS, no barriers — read
//  deg[g], gather the node's list. deg = the atomic counters (true
//  degree), consumed by k_node unchanged.
//  k_front proj + k_node + Wt1 prep unchanged from r14 (311us verified).
// 4 dispatches: k_pre, k_front [bins|prep|proj], k_aggf, k_node.

typedef __bf16 bf16;
typedef __attribute__((ext_vector_type(8))) __bf16 bf16x8;
typedef __attribute__((ext_vector_type(4))) __bf16 bf16x4v;
typedef __attribute__((ext_vector_type(4))) float floatx4;
typedef __attribute__((ext_vector_type(2))) float floatx2;

#define DD 128
#define HH 256
#define CAPN 64        // records per node per direction; mean 16, P(>=64)~2e-22

__device__ __forceinline__ bf16x8 ns8(const float* __restrict__ NS, int row, int col, int N) {
    bf16x8 v;
    if (row < N) {
        float4 f0 = *(const float4*)&NS[(size_t)row * DD + col];
        float4 f1 = *(const float4*)&NS[(size_t)row * DD + col + 4];
        v[0] = (bf16)f0.x; v[1] = (bf16)f0.y; v[2] = (bf16)f0.z; v[3] = (bf16)f0.w;
        v[4] = (bf16)f1.x; v[5] = (bf16)f1.y; v[6] = (bf16)f1.z; v[7] = (bf16)f1.w;
    } else {
        v = (bf16x8)(bf16)0.0f;
    }
    return v;
}

// ---------------- pre: Wt1 transpose + deg zero ----------------
__global__ void k_pre(const float* __restrict__ W1, const float* __restrict__ RW1,
                      bf16* __restrict__ Wt1, int* __restrict__ deg, int nzn) {
    const int b = blockIdx.x, t = threadIdx.x;
    if (b < 512) {                       // Wt1[n][k]: transposed W1/RW1 blocks
        int idx = b * 256 + t;
        int n = idx >> 7, k = idx & 127;
        float v;
        if (n < 256)      v = W1[k * 256 + n];
        else if (n < 512) v = W1[(128 + k) * 256 + (n - 256)];
        else if (n < 768) v = RW1[k * 256 + (n - 512)];
        else              v = RW1[(128 + k) * 256 + (n - 768)];
        Wt1[idx] = (bf16)v;
    } else {
        int i = (b - 512) * 256 + t;
        if (i < nzn) deg[i] = 0;
    }
}

// ---------------- fused front: bins | prep | proj ----------------
__global__ __launch_bounds__(256) void k_front(
    const float* __restrict__ NS, const int* __restrict__ from_idx,
    const int* __restrict__ to_idx, const float* __restrict__ ef,
    const float* __restrict__ W2, const float* __restrict__ RW2,
    const float* __restrict__ Wn1, const float* __restrict__ Wn2,
    const float* __restrict__ b2, const float* __restrict__ Rb2,
    const bf16* __restrict__ Wt1,
    int* __restrict__ deg, int2* __restrict__ binbuf,
    unsigned char* __restrict__ Pn, bf16* __restrict__ Pf,
    bf16* __restrict__ Wth, bf16* __restrict__ Wt2,
    float* __restrict__ u, float* __restrict__ ru,
    int E, int N, int NP, int BINB, int MB) {
    __shared__ __align__(16) unsigned char smem[30720];
    const int b = blockIdx.x, t = threadIdx.x;

    if (b < BINB) {
        // ---------- edge binning: direct per-node list append ----------
        const int e0 = b * 2048;
        int f[8], tt[8]; float w[8]; bool valid[8];
#pragma unroll
        for (int q = 0; q < 8; ++q) {
            int e = e0 + q * 256 + t;
            valid[q] = e < E;
            int ec = valid[q] ? e : 0;
            f[q] = from_idx[ec]; tt[q] = to_idx[ec]; w[q] = ef[ec];
        }
#pragma unroll
        for (int q = 0; q < 8; ++q) {
            if (valid[q]) {
                int wb = __float_as_int(w[q]);
                int s1 = atomicAdd(&deg[tt[q]], 1);
                if (s1 < CAPN)
                    binbuf[((size_t)tt[q] << 6) + s1] = make_int2(f[q] << 9, wb);
                int s2 = atomicAdd(&deg[NP + f[q]], 1);
                if (s2 < CAPN)
                    binbuf[((size_t)(NP + f[q]) << 6) + s2] = make_int2(tt[q] << 9, wb);
            }
        }
        return;
    }

    if (b < BINB + 769) {
        // ---------- weight prep (consumed only by k_node) ----------
        int bb = b - BINB;
        if (bb < 640) {                  // Wth[m][k]: W2@Wn1_top | RW2@Wn1_top | Wn1_bot
            int k = bb, m = t;
            float v;
            if (k < 512) {
                const float* Wsrc = (k < 256) ? W2 : RW2;
                int i = k & 255;
                float acc = 0.f;
                for (int j = 0; j < 256; ++j) acc += Wsrc[i * 256 + j] * Wn1[j * 256 + m];
                v = acc;
            } else {
                v = Wn1[(256 + k - 512) * 256 + m];
            }
            Wth[m * 640 + k] = (bf16)v;
        } else if (bb < 768) {           // Wt2[n][k] = Wn2^T
            int idx = (bb - 640) * 256 + t;
            int n = idx >> 8, k = idx & 255;
            Wt2[idx] = (bf16)Wn2[k * 128 + n];
        } else {                         // u = b2@Wn1_top, ru = Rb2@Wn1_top
            int m = t;
            float a = 0.f, c2 = 0.f;
            for (int j = 0; j < 256; ++j) {
                float w = Wn1[j * 256 + m];
                a += b2[j] * w;
                c2 += Rb2[j] * w;
            }
            u[m] = a;
            ru[m] = c2;
        }
        return;
    }

    // ---------- projection GEMM: 2 col-tiles per block, A reused ----------
    // XCD swizzle: launch ids 8 apart share a row-group (same XCD under
    // round-robin dispatch) so the NS panel stays L2-resident.
    {
        bf16 (*As)[64][40] = (bf16(*)[64][40])smem;                 // [2][64][40]
        bf16 (*Bs)[2][64][40] = (bf16(*)[2][64][40])(smem + 10240); // [cp][h][64][40]
        const int p = b - (BINB + 769);
        const int g = (p >> 6) * 8 + (p & 7);     // row-group
        if (g >= MB) return;
        const int row0 = g * 64;
        const int colp = ((p >> 3) & 7) * 128;    // two 64-col tiles: colp, colp+64
        const int wv = t >> 6, lane = t & 63;
        const int l15 = lane & 15, quad = lane >> 4;
        const int srow = t >> 2, kc = (t & 3) * 8;
        floatx4 acc[2][4] = {};
        for (int k0 = 0; k0 < DD; k0 += 64) {
            bf16x8 av0 = ns8(NS, row0 + srow, k0 + kc, N);
            bf16x8 av1 = ns8(NS, row0 + srow, k0 + 32 + kc, N);
            bf16x8 bv00 = *(const bf16x8*)&Wt1[(size_t)(colp + srow) * DD + k0 + kc];
            bf16x8 bv01 = *(const bf16x8*)&Wt1[(size_t)(colp + srow) * DD + k0 + 32 + kc];
            bf16x8 bv10 = *(const bf16x8*)&Wt1[(size_t)(colp + 64 + srow) * DD + k0 + kc];
            bf16x8 bv11 = *(const bf16x8*)&Wt1[(size_t)(colp + 64 + srow) * DD + k0 + 32 + kc];
            __syncthreads();
            *(bf16x8*)&As[0][srow][kc] = av0;
            *(bf16x8*)&As[1][srow][kc] = av1;
            *(bf16x8*)&Bs[0][0][srow][kc] = bv00;
            *(bf16x8*)&Bs[0][1][srow][kc] = bv01;
            *(bf16x8*)&Bs[1][0][srow][kc] = bv10;
            *(bf16x8*)&Bs[1][1][srow][kc] = bv11;
            __syncthreads();
#pragma unroll
            for (int h = 0; h < 2; ++h) {
                bf16x8 afr[4];
#pragma unroll
                for (int r = 0; r < 4; ++r)
                    afr[r] = *(const bf16x8*)&As[h][r * 16 + l15][quad * 8];
#pragma unroll
                for (int cp = 0; cp < 2; ++cp) {
                    bf16x8 bfr = *(const bf16x8*)&Bs[cp][h][wv * 16 + l15][quad * 8];
#pragma unroll
                    for (int r = 0; r < 4; ++r)
                        acc[cp][r] = __builtin_amdgcn_mfma_f32_16x16x32_bf16(afr[r], bfr, acc[cp][r], 0, 0, 0);
                }
            }
        }
#pragma unroll
        for (int cp = 0; cp < 2; ++cp) {
            const int ocol = colp + cp * 64 + wv * 16 + l15;  // [0,1024)
            const int ch = ocol & 255;
            const int half = (ocol >> 9) & 1;                 // 0=fwd pair, 1=rev pair
            const bool isNbr = ((ocol >> 8) & 1) == 0;        // fp8 nbr halves
#pragma unroll
            for (int r = 0; r < 4; ++r)
#pragma unroll
                for (int i = 0; i < 4; ++i) {
                    int orow = row0 + r * 16 + quad * 4 + i;
                    float v = acc[cp][r][i];
                    if (isNbr) {
                        int pk = __builtin_amdgcn_cvt_pk_fp8_f32(v, v, 0, false);
                        Pn[(size_t)orow * 512 + half * 256 + ch] = (unsigned char)(pk & 0xFF);
                    } else {
                        Pf[(size_t)orow * 512 + half * 256 + ch] = (bf16)v;
                    }
                }
        }
    }
}

// ---------------- aggregation: sort-free, per-node lists ----------------
// Grid = 2NP/16 blocks x 256 threads; each wave handles 4 node-direction
// keys; no LDS, no barriers. Records already per-node in binbuf.
__global__ __launch_bounds__(256) void k_aggf(
    const unsigned char* __restrict__ Pn, const bf16* __restrict__ Pf,
    const int2* __restrict__ binbuf, const int* __restrict__ deg,
    const float* __restrict__ W1, const float* __restrict__ b1,
    const float* __restrict__ RW1, const float* __restrict__ Rb1,
    bf16* __restrict__ S_to, bf16* __restrict__ S_fr, int NP) {
    const int t = threadIdx.x;
    const int wv = t >> 6, lane = t & 63, c = lane * 4;
    const int g0 = blockIdx.x * 16 + wv * 4;   // 4 keys per wave; NP%16==0 so
    const bool rev = g0 >= NP;                  // a block never straddles dirs
    const int fixoff = rev ? 256 : 0;     // into Pf row (elements)
    const int coff = (rev ? 256 : 0) + c; // into Pn row (bytes)
    const float* bb = rev ? Rb1 : b1;
    const float* wl = (rev ? RW1 : W1) + 65536;   // row 256 of [257,256]
    float4 bv = *(const float4*)&bb[c];
    float4 wv4 = *(const float4*)&wl[c];
    bf16* Sarr = rev ? S_fr : S_to;

#pragma unroll
    for (int kk = 0; kk < 4; ++kk) {
        const int g = g0 + kk;
        const int node = rev ? g - NP : g;
        int cnt = deg[g]; if (cnt > CAPN) cnt = CAPN;
        cnt = __builtin_amdgcn_readfirstlane(cnt);
        const int2* recs = binbuf + ((size_t)g << 6);
        bf16x4v pf = *(const bf16x4v*)&Pf[(size_t)node * 512 + fixoff + c];
        float fx0 = (float)pf[0] + bv.x;
        float fx1 = (float)pf[1] + bv.y;
        float fx2 = (float)pf[2] + bv.z;
        float fx3 = (float)pf[3] + bv.w;
        float e0 = 0.f, e1 = 0.f, e2 = 0.f, e3 = 0.f;
        float o0 = 0.f, o1 = 0.f, o2 = 0.f, o3 = 0.f;
        int j = 0;
        for (; j + 8 <= cnt; j += 8) {
            int2 rr[8]; int qq[8];
#pragma unroll
            for (int z = 0; z < 8; ++z) rr[z] = recs[j + z];
#pragma unroll
            for (int z = 0; z < 8; ++z)
                qq[z] = *(const int*)&Pn[(unsigned)rr[z].x + coff];
#pragma unroll
            for (int z = 0; z < 8; ++z) {
                float w = __int_as_float(rr[z].y);
                floatx2 lo = __builtin_amdgcn_cvt_pk_f32_fp8(qq[z], false);
                floatx2 hi = __builtin_amdgcn_cvt_pk_f32_fp8(qq[z], true);
                if (z & 1) {
                    o0 += fmaxf(__builtin_fmaf(w, wv4.x, fx0 + lo.x), 0.f);
                    o1 += fmaxf(__builtin_fmaf(w, wv4.y, fx1 + lo.y), 0.f);
                    o2 += fmaxf(__builtin_fmaf(w, wv4.z, fx2 + hi.x), 0.f);
                    o3 += fmaxf(__builtin_fmaf(w, wv4.w, fx3 + hi.y), 0.f);
                } else {
                    e0 += fmaxf(__builtin_fmaf(w, wv4.x, fx0 + lo.x), 0.f);
                    e1 += fmaxf(__builtin_fmaf(w, wv4.y, fx1 + lo.y), 0.f);
                    e2 += fmaxf(__builtin_fmaf(w, wv4.z, fx2 + hi.x), 0.f);
                    e3 += fmaxf(__builtin_fmaf(w, wv4.w, fx3 + hi.y), 0.f);
                }
            }
        }
        for (; j < cnt; ++j) {
            int2 r = recs[j];
            int q1 = *(const int*)&Pn[(unsigned)r.x + coff];
            float w = __int_as_float(r.y);
            floatx2 lo = __builtin_amdgcn_cvt_pk_f32_fp8(q1, false);
            floatx2 hi = __builtin_amdgcn_cvt_pk_f32_fp8(q1, true);
            e0 += fmaxf(__builtin_fmaf(w, wv4.x, fx0 + lo.x), 0.f);
            e1 += fmaxf(__builtin_fmaf(w, wv4.y, fx1 + lo.y), 0.f);
            e2 += fmaxf(__builtin_fmaf(w, wv4.z, fx2 + hi.x), 0.f);
            e3 += fmaxf(__builtin_fmaf(w, wv4.w, fx3 + hi.y), 0.f);
        }
        float a0 = e0 + o0, a1 = e1 + o1, a2 = e2 + o2, a3 = e3 + o3;
        bf16x4v o;
        o[0] = (bf16)a0; o[1] = (bf16)a1; o[2] = (bf16)a2; o[3] = (bf16)a3;
        *(bf16x4v*)&Sarr[(size_t)node * 256 + c] = o;
    }
}

// ---------------- fused node MLP (BK=32): Hid in LDS, out = Hid@Wt2^T + bn2 + NS ----------------
__global__ __launch_bounds__(256) void k_node(
    const bf16* __restrict__ S_to, const bf16* __restrict__ S_fr,
    const float* __restrict__ NS, const bf16* __restrict__ Wth,
    const bf16* __restrict__ Wt2,
    const float* __restrict__ u, const float* __restrict__ ru,
    const float* __restrict__ bn1, const float* __restrict__ bn2,
    const int* __restrict__ deg, float* __restrict__ out, int NP, int N) {
    __shared__ __align__(16) unsigned char smem[33792];   // max(As+Bs=25600, Hs=33792)
    bf16 (*As)[40]  = (bf16(*)[40])smem;                  // [64][40]
    bf16 (*Bs)[40]  = (bf16(*)[40])(smem + 5120);         // [256][40]
    bf16 (*Hs)[264] = (bf16(*)[264])smem;                 // [64][264]
    const int tid = threadIdx.x;
    const int wv = tid >> 6, lane = tid & 63;
    const int l15 = lane & 15, quad = lane >> 4;
    const int row0 = blockIdx.x * 64;
    const int srow = tid >> 2, kc = (tid & 3) * 8;
    floatx4 acc[4][4] = {};   // [colstrip][rowtile]; wave covers cols wv*64..+64
    const int arow = row0 + srow;
    for (int k0 = 0; k0 < 640; k0 += 32) {
        bf16x8 av;
        if (k0 < 512) {
            const bf16* S = (k0 < 256) ? S_to : S_fr;
            av = *(const bf16x8*)&S[(size_t)arow * 256 + (k0 & 255) + kc];
        } else {
            av = ns8(NS, arow, (k0 - 512) + kc, N);
        }
        bf16x8 bv[4];
#pragma unroll
        for (int j = 0; j < 4; ++j)
            bv[j] = *(const bf16x8*)&Wth[(size_t)(srow + 64 * j) * 640 + k0 + kc];
        __syncthreads();
        *(bf16x8*)&As[srow][kc] = av;
#pragma unroll
        for (int j = 0; j < 4; ++j)
            *(bf16x8*)&Bs[srow + 64 * j][kc] = bv[j];
        __syncthreads();
#pragma unroll
        for (int s = 0; s < 4; ++s) {
            bf16x8 bfr = *(const bf16x8*)&Bs[wv * 64 + s * 16 + l15][quad * 8];
#pragma unroll
            for (int r = 0; r < 4; ++r) {
                bf16x8 afr = *(const bf16x8*)&As[r * 16 + l15][quad * 8];
                acc[s][r] = __builtin_amdgcn_mfma_f32_16x16x32_bf16(afr, bfr, acc[s][r], 0, 0, 0);
            }
        }
    }
    __syncthreads();   // all As/Bs reads done before Hs overwrite
    // epilogue 1: deg terms + bias + relu -> Hs
#pragma unroll
    for (int s = 0; s < 4; ++s) {
        int col = wv * 64 + s * 16 + l15;
        float uc = u[col], rc = ru[col], bc = bn1[col];
#pragma unroll
        for (int r = 0; r < 4; ++r)
#pragma unroll
            for (int i = 0; i < 4; ++i) {
                int row = r * 16 + quad * 4 + i;
                float v = acc[s][r][i] + (float)deg[row0 + row] * uc
                        + (float)deg[NP + row0 + row] * rc + bc;
                Hs[row][col] = (bf16)fmaxf(v, 0.f);
            }
    }
    __syncthreads();
    // phase 2: out[64x128]; wave covers cols wv*32..+32 (2 strips)
    floatx4 acc2[2][4] = {};
    for (int k0 = 0; k0 < HH; k0 += 32) {
        bf16x8 afr[4];
#pragma unroll
        for (int r = 0; r < 4; ++r)
            afr[r] = *(const bf16x8*)&Hs[r * 16 + l15][k0 + quad * 8];
#pragma unroll
        for (int s = 0; s < 2; ++s) {
            int col = wv * 32 + s * 16 + l15;
            bf16x8 bfr = *(const bf16x8*)&Wt2[(size_t)col * HH + k0 + quad * 8];
#pragma unroll
            for (int r = 0; r < 4; ++r)
                acc2[s][r] = __builtin_amdgcn_mfma_f32_16x16x32_bf16(afr[r], bfr, acc2[s][r], 0, 0, 0);
        }
    }
#pragma unroll
    for (int s = 0; s < 2; ++s) {
        int ocol = wv * 32 + s * 16 + l15;
        float bb = bn2[ocol];
#pragma unroll
        for (int r = 0; r < 4; ++r)
#pragma unroll
            for (int i = 0; i < 4; ++i) {
                int orow = row0 + r * 16 + quad * 4 + i;
                if (orow < N)
                    out[(size_t)orow * DD + ocol] = acc2[s][r][i] + bb + NS[(size_t)orow * DD + ocol];
            }
    }
}

extern "C" void kernel_launch(void* const* d_in, const int* in_sizes, int n_in,
                              void* d_out, int out_size, void* d_ws, size_t ws_size,
                              hipStream_t stream) {
    const float* NS   = (const float*)d_in[0];
    const float* ef   = (const float*)d_in[1];
    const int* from_idx = (const int*)d_in[2];
    const int* to_idx   = (const int*)d_in[3];
    const float* W1  = (const float*)d_in[4];
    const float* b1  = (const float*)d_in[5];
    const float* W2  = (const float*)d_in[6];
    const float* b2  = (const float*)d_in[7];
    const float* RW1 = (const float*)d_in[8];
    const float* Rb1 = (const float*)d_in[9];
    const float* RW2 = (const float*)d_in[10];
    const float* Rb2 = (const float*)d_in[11];
    const float* Wn1 = (const float*)d_in[12];
    const float* bn1 = (const float*)d_in[13];
    const float* Wn2 = (const float*)d_in[14];
    const float* bn2 = (const float*)d_in[15];

    const int N  = in_sizes[0] / DD;
    const int E  = in_sizes[2];
    const int NP = ((N + 63) / 64) * 64;
    const int MB = NP / 64;
    const int BINB = (E + 2047) / 2048;
    const int FRONT = BINB + 769 + 64 * ((MB + 7) / 8);   // proj padded to x8 row-groups
    const int PREB = 512 + (2 * NP + 255) / 256;
    const int AGGB = (2 * NP) / 16;

    char* base = (char*)d_ws;
    size_t off_b = 0;
    auto alloc = [&](size_t b) { size_t o = off_b; off_b += (b + 255) & ~(size_t)255; return o; };
    unsigned char* Pn = (unsigned char*)(base + alloc((size_t)NP * 512));
    bf16* Pf   = (bf16*)(base + alloc((size_t)NP * 512 * 2));
    bf16* S_to = (bf16*)(base + alloc((size_t)NP * 256 * 2));
    bf16* S_fr = (bf16*)(base + alloc((size_t)NP * 256 * 2));
    int* deg   = (int*)(base + alloc((size_t)2 * NP * 4));
    int2* binbuf = (int2*)(base + alloc((size_t)2 * NP * CAPN * 8));
    bf16* Wt1 = (bf16*)(base + alloc(1024 * 128 * 2));
    bf16* Wth = (bf16*)(base + alloc(256 * 640 * 2));
    bf16* Wt2 = (bf16*)(base + alloc(128 * 256 * 2));
    float* u  = (float*)(base + alloc(256 * 4));
    float* ru = (float*)(base + alloc(256 * 4));

    k_pre<<<PREB, 256, 0, stream>>>(W1, RW1, Wt1, deg, 2 * NP);
    k_front<<<FRONT, 256, 0, stream>>>(NS, from_idx, to_idx, ef,
                                       W2, RW2, Wn1, Wn2, b2, Rb2, Wt1,
                                       deg, binbuf, Pn, Pf, Wth, Wt2, u, ru,
                                       E, N, NP, BINB, MB);
    k_aggf<<<AGGB, 256, 0, stream>>>(Pn, Pf, binbuf, deg, W1, b1, RW1, Rb1,
                                     S_to, S_fr, NP);
    k_node<<<MB, 256, 0, stream>>>(S_to, S_fr, NS, Wth, Wt2, u, ru, bn1, bn2,
                                   deg, (float*)d_out, NP, N);
}

// Round 10
// 319.975 us; speedup vs baseline: 1.4226x; 1.4226x over previous
//
#include <hip/hip_runtime.h>
#include <hip/hip_bf16.h>

// GraphPropLayer on MI355X — round 20: r14 baseline (311us, best verified)
//  with ONE contained change: k_aggf blocks 256 -> 128 threads (2 waves).
//  3128 blocks over 2048 resident slots was 1.53 scheduling rounds (58%
//  occupancy); with 16 x 128-thread blocks/CU it is 0.76 rounds — single
//  round, no quantized tail, finer-grained finish times. Body unchanged
//  (r14-verified): static key striding, LDS block scan, pre-shifted srec
//  byte offsets, even/odd accumulators, reg-held records (now 8/thread).
//  r19 lesson: per-node direct append killed bins (uncoalesced atomics+
//  stores, front 88->200) — r14's LDS-staged binning restored.
// 4 dispatches: k_pre, k_front [bins|prep|proj], k_aggf, k_node.

typedef __bf16 bf16;
typedef __attribute__((ext_vector_type(8))) __bf16 bf16x8;
typedef __attribute__((ext_vector_type(4))) __bf16 bf16x4v;
typedef __attribute__((ext_vector_type(4))) float floatx4;
typedef __attribute__((ext_vector_type(2))) float floatx2;

#define DD 128
#define HH 256
#define CAPB 800       // records per 32-node bin; mean 512, sigma 23 -> 12 sigma
#define MAXBINS 3200   // >= 2*NP/32 for N <= 51200

__device__ __forceinline__ bf16x8 ns8(const float* __restrict__ NS, int row, int col, int N) {
    bf16x8 v;
    if (row < N) {
        float4 f0 = *(const float4*)&NS[(size_t)row * DD + col];
        float4 f1 = *(const float4*)&NS[(size_t)row * DD + col + 4];
        v[0] = (bf16)f0.x; v[1] = (bf16)f0.y; v[2] = (bf16)f0.z; v[3] = (bf16)f0.w;
        v[4] = (bf16)f1.x; v[5] = (bf16)f1.y; v[6] = (bf16)f1.z; v[7] = (bf16)f1.w;
    } else {
        v = (bf16x8)(bf16)0.0f;
    }
    return v;
}

// ---------------- pre: Wt1 transpose + gcur zero ----------------
__global__ void k_pre(const float* __restrict__ W1, const float* __restrict__ RW1,
                      bf16* __restrict__ Wt1, int* __restrict__ gcur, int nzn) {
    const int b = blockIdx.x, t = threadIdx.x;
    if (b < 512) {                       // Wt1[n][k]: transposed W1/RW1 blocks
        int idx = b * 256 + t;
        int n = idx >> 7, k = idx & 127;
        float v;
        if (n < 256)      v = W1[k * 256 + n];
        else if (n < 512) v = W1[(128 + k) * 256 + (n - 256)];
        else if (n < 768) v = RW1[k * 256 + (n - 512)];
        else              v = RW1[(128 + k) * 256 + (n - 768)];
        Wt1[idx] = (bf16)v;
    } else {
        int i = (b - 512) * 256 + t;
        if (i < nzn) gcur[i] = 0;
    }
}

// ---------------- fused front: bins | prep | proj (r14 verbatim) ----------------
__global__ __launch_bounds__(256) void k_front(
    const float* __restrict__ NS, const int* __restrict__ from_idx,
    const int* __restrict__ to_idx, const float* __restrict__ ef,
    const float* __restrict__ W2, const float* __restrict__ RW2,
    const float* __restrict__ Wn1, const float* __restrict__ Wn2,
    const float* __restrict__ b2, const float* __restrict__ Rb2,
    const bf16* __restrict__ Wt1,
    int* __restrict__ gcur, int2* __restrict__ binbuf,
    unsigned char* __restrict__ Pn, bf16* __restrict__ Pf,
    bf16* __restrict__ Wth, bf16* __restrict__ Wt2,
    float* __restrict__ u, float* __restrict__ ru,
    int E, int N, int NP, int NBINS, int BINB, int MB) {
    __shared__ __align__(16) unsigned char smem[30720];
    const int b = blockIdx.x, t = threadIdx.x;

    if (b < BINB) {
        // ---------- edge binning: 2048 edges/block, 32-node bins ----------
        int* hist = (int*)smem;
        int* base = hist + MAXBINS;
        const int NBF = NP >> 5;
        for (int i = t; i < NBINS; i += 256) hist[i] = 0;
        __syncthreads();
        const int e0 = b * 2048;
        int f[8], tt[8]; float w[8]; bool valid[8];
#pragma unroll
        for (int q = 0; q < 8; ++q) {
            int e = e0 + q * 256 + t;
            valid[q] = e < E;
            int ec = valid[q] ? e : 0;
            f[q] = from_idx[ec]; tt[q] = to_idx[ec]; w[q] = ef[ec];
        }
#pragma unroll
        for (int q = 0; q < 8; ++q) {
            if (valid[q]) {
                atomicAdd(&hist[tt[q] >> 5], 1);
                atomicAdd(&hist[NBF + (f[q] >> 5)], 1);
            }
        }
        __syncthreads();
        for (int i = t; i < NBINS; i += 256) {
            int h = hist[i];
            base[i] = h ? atomicAdd(&gcur[i], h) : 0;
            hist[i] = 0;
        }
        __syncthreads();
#pragma unroll
        for (int q = 0; q < 8; ++q) {
            if (valid[q]) {
                int wb = __float_as_int(w[q]);
                int b1 = tt[q] >> 5;
                int r1 = base[b1] + atomicAdd(&hist[b1], 1);
                if (r1 < CAPB)
                    binbuf[(size_t)b1 * CAPB + r1] = make_int2(((tt[q] & 31) << 17) | f[q], wb);
                int b2i = NBF + (f[q] >> 5);
                int r2 = base[b2i] + atomicAdd(&hist[b2i], 1);
                if (r2 < CAPB)
                    binbuf[(size_t)b2i * CAPB + r2] = make_int2(((f[q] & 31) << 17) | tt[q], wb);
            }
        }
        return;
    }

    if (b < BINB + 769) {
        // ---------- weight prep (consumed only by k_node) ----------
        int bb = b - BINB;
        if (bb < 640) {                  // Wth[m][k]: W2@Wn1_top | RW2@Wn1_top | Wn1_bot
            int k = bb, m = t;
            float v;
            if (k < 512) {
                const float* Wsrc = (k < 256) ? W2 : RW2;
                int i = k & 255;
                float acc = 0.f;
                for (int j = 0; j < 256; ++j) acc += Wsrc[i * 256 + j] * Wn1[j * 256 + m];
                v = acc;
            } else {
                v = Wn1[(256 + k - 512) * 256 + m];
            }
            Wth[m * 640 + k] = (bf16)v;
        } else if (bb < 768) {           // Wt2[n][k] = Wn2^T
            int idx = (bb - 640) * 256 + t;
            int n = idx >> 8, k = idx & 255;
            Wt2[idx] = (bf16)Wn2[k * 128 + n];
        } else {                         // u = b2@Wn1_top, ru = Rb2@Wn1_top
            int m = t;
            float a = 0.f, c2 = 0.f;
            for (int j = 0; j < 256; ++j) {
                float w = Wn1[j * 256 + m];
                a += b2[j] * w;
                c2 += Rb2[j] * w;
            }
            u[m] = a;
            ru[m] = c2;
        }
        return;
    }

    // ---------- projection GEMM: 2 col-tiles per block, A reused ----------
    // XCD swizzle: launch ids 8 apart share a row-group (same XCD under
    // round-robin dispatch) so the NS panel stays L2-resident.
    {
        bf16 (*As)[64][40] = (bf16(*)[64][40])smem;                 // [2][64][40]
        bf16 (*Bs)[2][64][40] = (bf16(*)[2][64][40])(smem + 10240); // [cp][h][64][40]
        const int p = b - (BINB + 769);
        const int g = (p >> 6) * 8 + (p & 7);     // row-group
        if (g >= MB) return;
        const int row0 = g * 64;
        const int colp = ((p >> 3) & 7) * 128;    // two 64-col tiles: colp, colp+64
        const int wv = t >> 6, lane = t & 63;
        const int l15 = lane & 15, quad = lane >> 4;
        const int srow = t >> 2, kc = (t & 3) * 8;
        floatx4 acc[2][4] = {};
        for (int k0 = 0; k0 < DD; k0 += 64) {
            bf16x8 av0 = ns8(NS, row0 + srow, k0 + kc, N);
            bf16x8 av1 = ns8(NS, row0 + srow, k0 + 32 + kc, N);
            bf16x8 bv00 = *(const bf16x8*)&Wt1[(size_t)(colp + srow) * DD + k0 + kc];
            bf16x8 bv01 = *(const bf16x8*)&Wt1[(size_t)(colp + srow) * DD + k0 + 32 + kc];
            bf16x8 bv10 = *(const bf16x8*)&Wt1[(size_t)(colp + 64 + srow) * DD + k0 + kc];
            bf16x8 bv11 = *(const bf16x8*)&Wt1[(size_t)(colp + 64 + srow) * DD + k0 + 32 + kc];
            __syncthreads();
            *(bf16x8*)&As[0][srow][kc] = av0;
            *(bf16x8*)&As[1][srow][kc] = av1;
            *(bf16x8*)&Bs[0][0][srow][kc] = bv00;
            *(bf16x8*)&Bs[0][1][srow][kc] = bv01;
            *(bf16x8*)&Bs[1][0][srow][kc] = bv10;
            *(bf16x8*)&Bs[1][1][srow][kc] = bv11;
            __syncthreads();
#pragma unroll
            for (int h = 0; h < 2; ++h) {
                bf16x8 afr[4];
#pragma unroll
                for (int r = 0; r < 4; ++r)
                    afr[r] = *(const bf16x8*)&As[h][r * 16 + l15][quad * 8];
#pragma unroll
                for (int cp = 0; cp < 2; ++cp) {
                    bf16x8 bfr = *(const bf16x8*)&Bs[cp][h][wv * 16 + l15][quad * 8];
#pragma unroll
                    for (int r = 0; r < 4; ++r)
                        acc[cp][r] = __builtin_amdgcn_mfma_f32_16x16x32_bf16(afr[r], bfr, acc[cp][r], 0, 0, 0);
                }
            }
        }
#pragma unroll
        for (int cp = 0; cp < 2; ++cp) {
            const int ocol = colp + cp * 64 + wv * 16 + l15;  // [0,1024)
            const int ch = ocol & 255;
            const int half = (ocol >> 9) & 1;                 // 0=fwd pair, 1=rev pair
            const bool isNbr = ((ocol >> 8) & 1) == 0;        // fp8 nbr halves
#pragma unroll
            for (int r = 0; r < 4; ++r)
#pragma unroll
                for (int i = 0; i < 4; ++i) {
                    int orow = row0 + r * 16 + quad * 4 + i;
                    float v = acc[cp][r][i];
                    if (isNbr) {
                        int pk = __builtin_amdgcn_cvt_pk_fp8_f32(v, v, 0, false);
                        Pn[(size_t)orow * 512 + half * 256 + ch] = (unsigned char)(pk & 0xFF);
                    } else {
                        Pf[(size_t)orow * 512 + half * 256 + ch] = (bf16)v;
                    }
                }
        }
    }
}

// ---------------- aggregation: one 128-thread block per 32-node bin ----------------
// 2 waves/block -> 16 blocks/CU resident -> 3128 bins in ONE scheduling round
// (was 1.53 rounds at 256 threads). Body = r14-verified code; 8 reg-held
// records per thread; key striding 2.
__global__ __launch_bounds__(128) void k_aggf(
    const unsigned char* __restrict__ Pn, const bf16* __restrict__ Pf,
    const int2* __restrict__ binbuf, const int* __restrict__ gcnt,
    const float* __restrict__ W1, const float* __restrict__ b1,
    const float* __restrict__ RW1, const float* __restrict__ Rb1,
    bf16* __restrict__ S_to, bf16* __restrict__ S_fr,
    int* __restrict__ deg, int NP) {
    __shared__ int hist[32], kstart[32], cur[32], scanbuf[32];
    __shared__ int2 srec[CAPB];
    const int b = blockIdx.x, t = threadIdx.x;
    const int NBF = NP >> 5;
    const bool rev = b >= NBF;
    const int node0 = (rev ? b - NBF : b) << 5;
    int cnt = gcnt[b]; if (cnt > CAPB) cnt = CAPB;
    const int2* bin = binbuf + (size_t)b * CAPB;
    if (t < 32) hist[t] = 0;
    __syncthreads();
    // histogram; hold records in registers for the scatter phase (8/thread)
    int2 h[8]; bool pv[8];
#pragma unroll
    for (int i = 0; i < 8; ++i) {
        int idx = t + 128 * i;
        pv[i] = idx < cnt;
        h[i] = pv[i] ? bin[idx] : make_int2(0, 0);
    }
#pragma unroll
    for (int i = 0; i < 8; ++i)
        if (pv[i]) atomicAdd(&hist[((unsigned)h[i].x) >> 17], 1);
    __syncthreads();
    if (t < 32) scanbuf[t] = hist[t];
    __syncthreads();
    for (int d = 1; d < 32; d <<= 1) {
        int v = (t < 32 && t >= d) ? scanbuf[t - d] : 0;
        __syncthreads();
        if (t < 32) scanbuf[t] += v;
        __syncthreads();
    }
    if (t < 32) { kstart[t] = scanbuf[t] - hist[t]; cur[t] = scanbuf[t] - hist[t]; }
    __syncthreads();
    // scatter: srec.x holds the PRE-SHIFTED byte offset (node*512)
#pragma unroll
    for (int i = 0; i < 8; ++i)
        if (pv[i]) srec[atomicAdd(&cur[((unsigned)h[i].x) >> 17], 1)] =
            make_int2((int)((((unsigned)h[i].x) & 0x1FFFFu) << 9), h[i].y);
    __syncthreads();

    const int wv = t >> 6, lane = t & 63, c = lane * 4;
    const int fixoff = rev ? 256 : 0;     // into Pf row (elements)
    const int coff = (rev ? 256 : 0) + c; // into Pn row (bytes)
    const float* bb = rev ? Rb1 : b1;
    const float* wl = (rev ? RW1 : W1) + 65536;   // row 256 of [257,256]
    float4 bv = *(const float4*)&bb[c];
    float4 wv4 = *(const float4*)&wl[c];
    bf16* Sarr = rev ? S_fr : S_to;

    for (int key = wv; key < 32; key += 2) {
        const int node = node0 + key;
        bf16x4v pf = *(const bf16x4v*)&Pf[(size_t)node * 512 + fixoff + c];
        float fx0 = (float)pf[0] + bv.x;
        float fx1 = (float)pf[1] + bv.y;
        float fx2 = (float)pf[2] + bv.z;
        float fx3 = (float)pf[3] + bv.w;
        const int beg = kstart[key], kc2 = hist[key], end = beg + kc2;
        float e0 = 0.f, e1 = 0.f, e2 = 0.f, e3 = 0.f;
        float o0 = 0.f, o1 = 0.f, o2 = 0.f, o3 = 0.f;
        int j = beg;
        for (; j + 8 <= end; j += 8) {
            int2 rr[8]; int qq[8];
#pragma unroll
            for (int z = 0; z < 8; ++z) rr[z] = srec[j + z];
#pragma unroll
            for (int z = 0; z < 8; ++z)
                qq[z] = *(const int*)&Pn[(unsigned)rr[z].x + coff];
#pragma unroll
            for (int z = 0; z < 8; ++z) {
                float w = __int_as_float(rr[z].y);
                floatx2 lo = __builtin_amdgcn_cvt_pk_f32_fp8(qq[z], false);
                floatx2 hi = __builtin_amdgcn_cvt_pk_f32_fp8(qq[z], true);
                if (z & 1) {
                    o0 += fmaxf(__builtin_fmaf(w, wv4.x, fx0 + lo.x), 0.f);
                    o1 += fmaxf(__builtin_fmaf(w, wv4.y, fx1 + lo.y), 0.f);
                    o2 += fmaxf(__builtin_fmaf(w, wv4.z, fx2 + hi.x), 0.f);
                    o3 += fmaxf(__builtin_fmaf(w, wv4.w, fx3 + hi.y), 0.f);
                } else {
                    e0 += fmaxf(__builtin_fmaf(w, wv4.x, fx0 + lo.x), 0.f);
                    e1 += fmaxf(__builtin_fmaf(w, wv4.y, fx1 + lo.y), 0.f);
                    e2 += fmaxf(__builtin_fmaf(w, wv4.z, fx2 + hi.x), 0.f);
                    e3 += fmaxf(__builtin_fmaf(w, wv4.w, fx3 + hi.y), 0.f);
                }
            }
        }
        for (; j < end; ++j) {
            int2 r = srec[j];
            int q1 = *(const int*)&Pn[(unsigned)r.x + coff];
            float w = __int_as_float(r.y);
            floatx2 lo = __builtin_amdgcn_cvt_pk_f32_fp8(q1, false);
            floatx2 hi = __builtin_amdgcn_cvt_pk_f32_fp8(q1, true);
            e0 += fmaxf(__builtin_fmaf(w, wv4.x, fx0 + lo.x), 0.f);
            e1 += fmaxf(__builtin_fmaf(w, wv4.y, fx1 + lo.y), 0.f);
            e2 += fmaxf(__builtin_fmaf(w, wv4.z, fx2 + hi.x), 0.f);
            e3 += fmaxf(__builtin_fmaf(w, wv4.w, fx3 + hi.y), 0.f);
        }
        float a0 = e0 + o0, a1 = e1 + o1, a2 = e2 + o2, a3 = e3 + o3;
        bf16x4v o;
        o[0] = (bf16)a0; o[1] = (bf16)a1; o[2] = (bf16)a2; o[3] = (bf16)a3;
        *(bf16x4v*)&Sarr[(size_t)node * 256 + c] = o;
        if (lane == 0) deg[(rev ? NP : 0) + node] = kc2;
    }
}

// ---------------- fused node MLP (BK=32): Hid in LDS, out = Hid@Wt2^T + bn2 + NS ----------------
__global__ __launch_bounds__(256) void k_node(
    const bf16* __restrict__ S_to, const bf16* __restrict__ S_fr,
    const float* __restrict__ NS, const bf16* __restrict__ Wth,
    const bf16* __restrict__ Wt2,
    const float* __restrict__ u, const float* __restrict__ ru,
    const float* __restrict__ bn1, const float* __restrict__ bn2,
    const int* __restrict__ deg, float* __restrict__ out, int NP, int N) {
    __shared__ __align__(16) unsigned char smem[33792];   // max(As+Bs=25600, Hs=33792)
    bf16 (*As)[40]  = (bf16(*)[40])smem;                  // [64][40]
    bf16 (*Bs)[40]  = (bf16(*)[40])(smem + 5120);         // [256][40]
    bf16 (*Hs)[264] = (bf16(*)[264])smem;                 // [64][264]
    const int tid = threadIdx.x;
    const int wv = tid >> 6, lane = tid & 63;
    const int l15 = lane & 15, quad = lane >> 4;
    const int row0 = blockIdx.x * 64;
    const int srow = tid >> 2, kc = (tid & 3) * 8;
    floatx4 acc[4][4] = {};   // [colstrip][rowtile]; wave covers cols wv*64..+64
    const int arow = row0 + srow;
    for (int k0 = 0; k0 < 640; k0 += 32) {
        bf16x8 av;
        if (k0 < 512) {
            const bf16* S = (k0 < 256) ? S_to : S_fr;
            av = *(const bf16x8*)&S[(size_t)arow * 256 + (k0 & 255) + kc];
        } else {
            av = ns8(NS, arow, (k0 - 512) + kc, N);
        }
        bf16x8 bv[4];
#pragma unroll
        for (int j = 0; j < 4; ++j)
            bv[j] = *(const bf16x8*)&Wth[(size_t)(srow + 64 * j) * 640 + k0 + kc];
        __syncthreads();
        *(bf16x8*)&As[srow][kc] = av;
#pragma unroll
        for (int j = 0; j < 4; ++j)
            *(bf16x8*)&Bs[srow + 64 * j][kc] = bv[j];
        __syncthreads();
#pragma unroll
        for (int s = 0; s < 4; ++s) {
            bf16x8 bfr = *(const bf16x8*)&Bs[wv * 64 + s * 16 + l15][quad * 8];
#pragma unroll
            for (int r = 0; r < 4; ++r) {
                bf16x8 afr = *(const bf16x8*)&As[r * 16 + l15][quad * 8];
                acc[s][r] = __builtin_amdgcn_mfma_f32_16x16x32_bf16(afr, bfr, acc[s][r], 0, 0, 0);
            }
        }
    }
    __syncthreads();   // all As/Bs reads done before Hs overwrite
    // epilogue 1: deg terms + bias + relu -> Hs
#pragma unroll
    for (int s = 0; s < 4; ++s) {
        int col = wv * 64 + s * 16 + l15;
        float uc = u[col], rc = ru[col], bc = bn1[col];
#pragma unroll
        for (int r = 0; r < 4; ++r)
#pragma unroll
            for (int i = 0; i < 4; ++i) {
                int row = r * 16 + quad * 4 + i;
                float v = acc[s][r][i] + (float)deg[row0 + row] * uc
                        + (float)deg[NP + row0 + row] * rc + bc;
                Hs[row][col] = (bf16)fmaxf(v, 0.f);
            }
    }
    __syncthreads();
    // phase 2: out[64x128]; wave covers cols wv*32..+32 (2 strips)
    floatx4 acc2[2][4] = {};
    for (int k0 = 0; k0 < HH; k0 += 32) {
        bf16x8 afr[4];
#pragma unroll
        for (int r = 0; r < 4; ++r)
            afr[r] = *(const bf16x8*)&Hs[r * 16 + l15][k0 + quad * 8];
#pragma unroll
        for (int s = 0; s < 2; ++s) {
            int col = wv * 32 + s * 16 + l15;
            bf16x8 bfr = *(const bf16x8*)&Wt2[(size_t)col * HH + k0 + quad * 8];
#pragma unroll
            for (int r = 0; r < 4; ++r)
                acc2[s][r] = __builtin_amdgcn_mfma_f32_16x16x32_bf16(afr[r], bfr, acc2[s][r], 0, 0, 0);
        }
    }
#pragma unroll
    for (int s = 0; s < 2; ++s) {
        int ocol = wv * 32 + s * 16 + l15;
        float bb = bn2[ocol];
#pragma unroll
        for (int r = 0; r < 4; ++r)
#pragma unroll
            for (int i = 0; i < 4; ++i) {
                int orow = row0 + r * 16 + quad * 4 + i;
                if (orow < N)
                    out[(size_t)orow * DD + ocol] = acc2[s][r][i] + bb + NS[(size_t)orow * DD + ocol];
            }
    }
}

extern "C" void kernel_launch(void* const* d_in, const int* in_sizes, int n_in,
                              void* d_out, int out_size, void* d_ws, size_t ws_size,
                              hipStream_t stream) {
    const float* NS   = (const float*)d_in[0];
    const float* ef   = (const float*)d_in[1];
    const int* from_idx = (const int*)d_in[2];
    const int* to_idx   = (const int*)d_in[3];
    const float* W1  = (const float*)d_in[4];
    const float* b1  = (const float*)d_in[5];
    const float* W2  = (const float*)d_in[6];
    const float* b2  = (const float*)d_in[7];
    const float* RW1 = (const float*)d_in[8];
    const float* Rb1 = (const float*)d_in[9];
    const float* RW2 = (const float*)d_in[10];
    const float* Rb2 = (const float*)d_in[11];
    const float* Wn1 = (const float*)d_in[12];
    const float* bn1 = (const float*)d_in[13];
    const float* Wn2 = (const float*)d_in[14];
    const float* bn2 = (const float*)d_in[15];

    const int N  = in_sizes[0] / DD;
    const int E  = in_sizes[2];
    const int NP = ((N + 63) / 64) * 64;
    const int MB = NP / 64;
    const int NBF = NP / 32;
    const int NBINS = 2 * NBF;
    const int BINB = (E + 2047) / 2048;
    const int FRONT = BINB + 769 + 64 * ((MB + 7) / 8);   // proj padded to x8 row-groups
    const int PREB = 512 + (NBINS + 255) / 256;

    char* base = (char*)d_ws;
    size_t off_b = 0;
    auto alloc = [&](size_t b) { size_t o = off_b; off_b += (b + 255) & ~(size_t)255; return o; };
    unsigned char* Pn = (unsigned char*)(base + alloc((size_t)NP * 512));
    bf16* Pf   = (bf16*)(base + alloc((size_t)NP * 512 * 2));
    bf16* S_to = (bf16*)(base + alloc((size_t)NP * 256 * 2));
    bf16* S_fr = (bf16*)(base + alloc((size_t)NP * 256 * 2));
    int* deg   = (int*)(base + alloc((size_t)2 * NP * 4));
    int* gcur  = (int*)(base + alloc((size_t)NBINS * 4));
    int2* binbuf = (int2*)(base + alloc((size_t)NBINS * CAPB * 8));
    bf16* Wt1 = (bf16*)(base + alloc(1024 * 128 * 2));
    bf16* Wth = (bf16*)(base + alloc(256 * 640 * 2));
    bf16* Wt2 = (bf16*)(base + alloc(128 * 256 * 2));
    float* u  = (float*)(base + alloc(256 * 4));
    float* ru = (float*)(base + alloc(256 * 4));

    k_pre<<<PREB, 256, 0, stream>>>(W1, RW1, Wt1, gcur, NBINS);
    k_front<<<FRONT, 256, 0, stream>>>(NS, from_idx, to_idx, ef,
                                       W2, RW2, Wn1, Wn2, b2, Rb2, Wt1,
                                       gcur, binbuf, Pn, Pf, Wth, Wt2, u, ru,
                                       E, N, NP, NBINS, BINB, MB);
    k_aggf<<<NBINS, 128, 0, stream>>>(Pn, Pf, binbuf, gcur, W1, b1, RW1, Rb1,
                                      S_to, S_fr, deg, NP);
    k_node<<<MB, 256, 0, stream>>>(S_to, S_fr, NS, Wth, Wt2, u, ru, bn1, bn2,
                                   deg, (float*)d_out, NP, N);
}

// Round 11
// 319.419 us; speedup vs baseline: 1.4250x; 1.0017x over previous
//
#include <hip/hip_runtime.h>
#include <hip/hip_bf16.h>

// GraphPropLayer on MI355X — round 21: r14 baseline restored (311us, best
//  verified across 7 structural variants — all regressed: pk-f32 (+9),
//  split (+15), persistent proj (+15), work-stealing (+43), per-node bins
//  (+144), 128-thread aggf (+9)). One zero-risk micro-trim added:
//  k_aggf software-pipelines the per-key Pf load (next key's Pf read
//  issued before current key's gather loop) to hide its ~300-500cy
//  latency under the gather. Everything else byte-identical to r14.
// 4 dispatches: k_pre, k_front [bins|prep|proj], k_aggf, k_node.

typedef __bf16 bf16;
typedef __attribute__((ext_vector_type(8))) __bf16 bf16x8;
typedef __attribute__((ext_vector_type(4))) __bf16 bf16x4v;
typedef __attribute__((ext_vector_type(4))) float floatx4;
typedef __attribute__((ext_vector_type(2))) float floatx2;

#define DD 128
#define HH 256
#define CAPB 800       // records per 32-node bin; mean 512, sigma 23 -> 12 sigma
#define MAXBINS 3200   // >= 2*NP/32 for N <= 51200

__device__ __forceinline__ bf16x8 ns8(const float* __restrict__ NS, int row, int col, int N) {
    bf16x8 v;
    if (row < N) {
        float4 f0 = *(const float4*)&NS[(size_t)row * DD + col];
        float4 f1 = *(const float4*)&NS[(size_t)row * DD + col + 4];
        v[0] = (bf16)f0.x; v[1] = (bf16)f0.y; v[2] = (bf16)f0.z; v[3] = (bf16)f0.w;
        v[4] = (bf16)f1.x; v[5] = (bf16)f1.y; v[6] = (bf16)f1.z; v[7] = (bf16)f1.w;
    } else {
        v = (bf16x8)(bf16)0.0f;
    }
    return v;
}

// ---------------- pre: Wt1 transpose + gcur zero ----------------
__global__ void k_pre(const float* __restrict__ W1, const float* __restrict__ RW1,
                      bf16* __restrict__ Wt1, int* __restrict__ gcur, int nzn) {
    const int b = blockIdx.x, t = threadIdx.x;
    if (b < 512) {                       // Wt1[n][k]: transposed W1/RW1 blocks
        int idx = b * 256 + t;
        int n = idx >> 7, k = idx & 127;
        float v;
        if (n < 256)      v = W1[k * 256 + n];
        else if (n < 512) v = W1[(128 + k) * 256 + (n - 256)];
        else if (n < 768) v = RW1[k * 256 + (n - 512)];
        else              v = RW1[(128 + k) * 256 + (n - 768)];
        Wt1[idx] = (bf16)v;
    } else {
        int i = (b - 512) * 256 + t;
        if (i < nzn) gcur[i] = 0;
    }
}

// ---------------- fused front: bins | prep | proj (r14 verbatim) ----------------
__global__ __launch_bounds__(256) void k_front(
    const float* __restrict__ NS, const int* __restrict__ from_idx,
    const int* __restrict__ to_idx, const float* __restrict__ ef,
    const float* __restrict__ W2, const float* __restrict__ RW2,
    const float* __restrict__ Wn1, const float* __restrict__ Wn2,
    const float* __restrict__ b2, const float* __restrict__ Rb2,
    const bf16* __restrict__ Wt1,
    int* __restrict__ gcur, int2* __restrict__ binbuf,
    unsigned char* __restrict__ Pn, bf16* __restrict__ Pf,
    bf16* __restrict__ Wth, bf16* __restrict__ Wt2,
    float* __restrict__ u, float* __restrict__ ru,
    int E, int N, int NP, int NBINS, int BINB, int MB) {
    __shared__ __align__(16) unsigned char smem[30720];
    const int b = blockIdx.x, t = threadIdx.x;

    if (b < BINB) {
        // ---------- edge binning: 2048 edges/block, 32-node bins ----------
        int* hist = (int*)smem;
        int* base = hist + MAXBINS;
        const int NBF = NP >> 5;
        for (int i = t; i < NBINS; i += 256) hist[i] = 0;
        __syncthreads();
        const int e0 = b * 2048;
        int f[8], tt[8]; float w[8]; bool valid[8];
#pragma unroll
        for (int q = 0; q < 8; ++q) {
            int e = e0 + q * 256 + t;
            valid[q] = e < E;
            int ec = valid[q] ? e : 0;
            f[q] = from_idx[ec]; tt[q] = to_idx[ec]; w[q] = ef[ec];
        }
#pragma unroll
        for (int q = 0; q < 8; ++q) {
            if (valid[q]) {
                atomicAdd(&hist[tt[q] >> 5], 1);
                atomicAdd(&hist[NBF + (f[q] >> 5)], 1);
            }
        }
        __syncthreads();
        for (int i = t; i < NBINS; i += 256) {
            int h = hist[i];
            base[i] = h ? atomicAdd(&gcur[i], h) : 0;
            hist[i] = 0;
        }
        __syncthreads();
#pragma unroll
        for (int q = 0; q < 8; ++q) {
            if (valid[q]) {
                int wb = __float_as_int(w[q]);
                int b1 = tt[q] >> 5;
                int r1 = base[b1] + atomicAdd(&hist[b1], 1);
                if (r1 < CAPB)
                    binbuf[(size_t)b1 * CAPB + r1] = make_int2(((tt[q] & 31) << 17) | f[q], wb);
                int b2i = NBF + (f[q] >> 5);
                int r2 = base[b2i] + atomicAdd(&hist[b2i], 1);
                if (r2 < CAPB)
                    binbuf[(size_t)b2i * CAPB + r2] = make_int2(((f[q] & 31) << 17) | tt[q], wb);
            }
        }
        return;
    }

    if (b < BINB + 769) {
        // ---------- weight prep (consumed only by k_node) ----------
        int bb = b - BINB;
        if (bb < 640) {                  // Wth[m][k]: W2@Wn1_top | RW2@Wn1_top | Wn1_bot
            int k = bb, m = t;
            float v;
            if (k < 512) {
                const float* Wsrc = (k < 256) ? W2 : RW2;
                int i = k & 255;
                float acc = 0.f;
                for (int j = 0; j < 256; ++j) acc += Wsrc[i * 256 + j] * Wn1[j * 256 + m];
                v = acc;
            } else {
                v = Wn1[(256 + k - 512) * 256 + m];
            }
            Wth[m * 640 + k] = (bf16)v;
        } else if (bb < 768) {           // Wt2[n][k] = Wn2^T
            int idx = (bb - 640) * 256 + t;
            int n = idx >> 8, k = idx & 255;
            Wt2[idx] = (bf16)Wn2[k * 128 + n];
        } else {                         // u = b2@Wn1_top, ru = Rb2@Wn1_top
            int m = t;
            float a = 0.f, c2 = 0.f;
            for (int j = 0; j < 256; ++j) {
                float w = Wn1[j * 256 + m];
                a += b2[j] * w;
                c2 += Rb2[j] * w;
            }
            u[m] = a;
            ru[m] = c2;
        }
        return;
    }

    // ---------- projection GEMM: 2 col-tiles per block, A reused ----------
    // XCD swizzle: launch ids 8 apart share a row-group (same XCD under
    // round-robin dispatch) so the NS panel stays L2-resident.
    {
        bf16 (*As)[64][40] = (bf16(*)[64][40])smem;                 // [2][64][40]
        bf16 (*Bs)[2][64][40] = (bf16(*)[2][64][40])(smem + 10240); // [cp][h][64][40]
        const int p = b - (BINB + 769);
        const int g = (p >> 6) * 8 + (p & 7);     // row-group
        if (g >= MB) return;
        const int row0 = g * 64;
        const int colp = ((p >> 3) & 7) * 128;    // two 64-col tiles: colp, colp+64
        const int wv = t >> 6, lane = t & 63;
        const int l15 = lane & 15, quad = lane >> 4;
        const int srow = t >> 2, kc = (t & 3) * 8;
        floatx4 acc[2][4] = {};
        for (int k0 = 0; k0 < DD; k0 += 64) {
            bf16x8 av0 = ns8(NS, row0 + srow, k0 + kc, N);
            bf16x8 av1 = ns8(NS, row0 + srow, k0 + 32 + kc, N);
            bf16x8 bv00 = *(const bf16x8*)&Wt1[(size_t)(colp + srow) * DD + k0 + kc];
            bf16x8 bv01 = *(const bf16x8*)&Wt1[(size_t)(colp + srow) * DD + k0 + 32 + kc];
            bf16x8 bv10 = *(const bf16x8*)&Wt1[(size_t)(colp + 64 + srow) * DD + k0 + kc];
            bf16x8 bv11 = *(const bf16x8*)&Wt1[(size_t)(colp + 64 + srow) * DD + k0 + 32 + kc];
            __syncthreads();
            *(bf16x8*)&As[0][srow][kc] = av0;
            *(bf16x8*)&As[1][srow][kc] = av1;
            *(bf16x8*)&Bs[0][0][srow][kc] = bv00;
            *(bf16x8*)&Bs[0][1][srow][kc] = bv01;
            *(bf16x8*)&Bs[1][0][srow][kc] = bv10;
            *(bf16x8*)&Bs[1][1][srow][kc] = bv11;
            __syncthreads();
#pragma unroll
            for (int h = 0; h < 2; ++h) {
                bf16x8 afr[4];
#pragma unroll
                for (int r = 0; r < 4; ++r)
                    afr[r] = *(const bf16x8*)&As[h][r * 16 + l15][quad * 8];
#pragma unroll
                for (int cp = 0; cp < 2; ++cp) {
                    bf16x8 bfr = *(const bf16x8*)&Bs[cp][h][wv * 16 + l15][quad * 8];
#pragma unroll
                    for (int r = 0; r < 4; ++r)
                        acc[cp][r] = __builtin_amdgcn_mfma_f32_16x16x32_bf16(afr[r], bfr, acc[cp][r], 0, 0, 0);
                }
            }
        }
#pragma unroll
        for (int cp = 0; cp < 2; ++cp) {
            const int ocol = colp + cp * 64 + wv * 16 + l15;  // [0,1024)
            const int ch = ocol & 255;
            const int half = (ocol >> 9) & 1;                 // 0=fwd pair, 1=rev pair
            const bool isNbr = ((ocol >> 8) & 1) == 0;        // fp8 nbr halves
#pragma unroll
            for (int r = 0; r < 4; ++r)
#pragma unroll
                for (int i = 0; i < 4; ++i) {
                    int orow = row0 + r * 16 + quad * 4 + i;
                    float v = acc[cp][r][i];
                    if (isNbr) {
                        int pk = __builtin_amdgcn_cvt_pk_fp8_f32(v, v, 0, false);
                        Pn[(size_t)orow * 512 + half * 256 + ch] = (unsigned char)(pk & 0xFF);
                    } else {
                        Pf[(size_t)orow * 512 + half * 256 + ch] = (bf16)v;
                    }
                }
        }
    }
}

// ---------------- aggregation: one block per 32-node bin ----------------
// r14 structure: static key striding, LDS block scan, pre-shifted srec
// byte offsets, even/odd accumulators, reg-held records. NEW: per-key Pf
// load software-pipelined (next key's Pf issued before current gather).
__global__ __launch_bounds__(256) void k_aggf(
    const unsigned char* __restrict__ Pn, const bf16* __restrict__ Pf,
    const int2* __restrict__ binbuf, const int* __restrict__ gcnt,
    const float* __restrict__ W1, const float* __restrict__ b1,
    const float* __restrict__ RW1, const float* __restrict__ Rb1,
    bf16* __restrict__ S_to, bf16* __restrict__ S_fr,
    int* __restrict__ deg, int NP) {
    __shared__ int hist[32], kstart[32], cur[32], scanbuf[32];
    __shared__ int2 srec[CAPB];
    const int b = blockIdx.x, t = threadIdx.x;
    const int NBF = NP >> 5;
    const bool rev = b >= NBF;
    const int node0 = (rev ? b - NBF : b) << 5;
    int cnt = gcnt[b]; if (cnt > CAPB) cnt = CAPB;
    const int2* bin = binbuf + (size_t)b * CAPB;
    if (t < 32) hist[t] = 0;
    __syncthreads();
    // histogram; hold records in registers for the scatter phase
    int2 h0 = make_int2(0, 0), h1 = h0, h2 = h0, h3 = h0;
    const bool p0 = t < cnt, p1 = t + 256 < cnt, p2 = t + 512 < cnt, p3 = t + 768 < cnt;
    if (p0) { h0 = bin[t];       atomicAdd(&hist[((unsigned)h0.x) >> 17], 1); }
    if (p1) { h1 = bin[t + 256]; atomicAdd(&hist[((unsigned)h1.x) >> 17], 1); }
    if (p2) { h2 = bin[t + 512]; atomicAdd(&hist[((unsigned)h2.x) >> 17], 1); }
    if (p3) { h3 = bin[t + 768]; atomicAdd(&hist[((unsigned)h3.x) >> 17], 1); }
    __syncthreads();
    if (t < 32) scanbuf[t] = hist[t];
    __syncthreads();
    for (int d = 1; d < 32; d <<= 1) {
        int v = (t < 32 && t >= d) ? scanbuf[t - d] : 0;
        __syncthreads();
        if (t < 32) scanbuf[t] += v;
        __syncthreads();
    }
    if (t < 32) { kstart[t] = scanbuf[t] - hist[t]; cur[t] = scanbuf[t] - hist[t]; }
    __syncthreads();
    // scatter: srec.x holds the PRE-SHIFTED byte offset (node*512)
    if (p0) srec[atomicAdd(&cur[((unsigned)h0.x) >> 17], 1)] =
        make_int2((int)((((unsigned)h0.x) & 0x1FFFFu) << 9), h0.y);
    if (p1) srec[atomicAdd(&cur[((unsigned)h1.x) >> 17], 1)] =
        make_int2((int)((((unsigned)h1.x) & 0x1FFFFu) << 9), h1.y);
    if (p2) srec[atomicAdd(&cur[((unsigned)h2.x) >> 17], 1)] =
        make_int2((int)((((unsigned)h2.x) & 0x1FFFFu) << 9), h2.y);
    if (p3) srec[atomicAdd(&cur[((unsigned)h3.x) >> 17], 1)] =
        make_int2((int)((((unsigned)h3.x) & 0x1FFFFu) << 9), h3.y);
    __syncthreads();

    const int wv = t >> 6, lane = t & 63, c = lane * 4;
    const int fixoff = rev ? 256 : 0;     // into Pf row (elements)
    const int coff = (rev ? 256 : 0) + c; // into Pn row (bytes)
    const float* bb = rev ? Rb1 : b1;
    const float* wl = (rev ? RW1 : W1) + 65536;   // row 256 of [257,256]
    float4 bv = *(const float4*)&bb[c];
    float4 wv4 = *(const float4*)&wl[c];
    bf16* Sarr = rev ? S_fr : S_to;

    // software-pipelined Pf: issue key's load one iteration ahead
    bf16x4v pf_n = *(const bf16x4v*)&Pf[(size_t)(node0 + wv) * 512 + fixoff + c];
    for (int key = wv; key < 32; key += 4) {
        const int node = node0 + key;
        bf16x4v pf = pf_n;
        if (key + 4 < 32)
            pf_n = *(const bf16x4v*)&Pf[(size_t)(node + 4) * 512 + fixoff + c];
        float fx0 = (float)pf[0] + bv.x;
        float fx1 = (float)pf[1] + bv.y;
        float fx2 = (float)pf[2] + bv.z;
        float fx3 = (float)pf[3] + bv.w;
        const int beg = kstart[key], kc2 = hist[key], end = beg + kc2;
        float e0 = 0.f, e1 = 0.f, e2 = 0.f, e3 = 0.f;
        float o0 = 0.f, o1 = 0.f, o2 = 0.f, o3 = 0.f;
        int j = beg;
        for (; j + 8 <= end; j += 8) {
            int2 rr[8]; int qq[8];
#pragma unroll
            for (int z = 0; z < 8; ++z) rr[z] = srec[j + z];
#pragma unroll
            for (int z = 0; z < 8; ++z)
                qq[z] = *(const int*)&Pn[(unsigned)rr[z].x + coff];
#pragma unroll
            for (int z = 0; z < 8; ++z) {
                float w = __int_as_float(rr[z].y);
                floatx2 lo = __builtin_amdgcn_cvt_pk_f32_fp8(qq[z], false);
                floatx2 hi = __builtin_amdgcn_cvt_pk_f32_fp8(qq[z], true);
                if (z & 1) {
                    o0 += fmaxf(__builtin_fmaf(w, wv4.x, fx0 + lo.x), 0.f);
                    o1 += fmaxf(__builtin_fmaf(w, wv4.y, fx1 + lo.y), 0.f);
                    o2 += fmaxf(__builtin_fmaf(w, wv4.z, fx2 + hi.x), 0.f);
                    o3 += fmaxf(__builtin_fmaf(w, wv4.w, fx3 + hi.y), 0.f);
                } else {
                    e0 += fmaxf(__builtin_fmaf(w, wv4.x, fx0 + lo.x), 0.f);
                    e1 += fmaxf(__builtin_fmaf(w, wv4.y, fx1 + lo.y), 0.f);
                    e2 += fmaxf(__builtin_fmaf(w, wv4.z, fx2 + hi.x), 0.f);
                    e3 += fmaxf(__builtin_fmaf(w, wv4.w, fx3 + hi.y), 0.f);
                }
            }
        }
        for (; j < end; ++j) {
            int2 r = srec[j];
            int q1 = *(const int*)&Pn[(unsigned)r.x + coff];
            float w = __int_as_float(r.y);
            floatx2 lo = __builtin_amdgcn_cvt_pk_f32_fp8(q1, false);
            floatx2 hi = __builtin_amdgcn_cvt_pk_f32_fp8(q1, true);
            e0 += fmaxf(__builtin_fmaf(w, wv4.x, fx0 + lo.x), 0.f);
            e1 += fmaxf(__builtin_fmaf(w, wv4.y, fx1 + lo.y), 0.f);
            e2 += fmaxf(__builtin_fmaf(w, wv4.z, fx2 + hi.x), 0.f);
            e3 += fmaxf(__builtin_fmaf(w, wv4.w, fx3 + hi.y), 0.f);
        }
        float a0 = e0 + o0, a1 = e1 + o1, a2 = e2 + o2, a3 = e3 + o3;
        bf16x4v o;
        o[0] = (bf16)a0; o[1] = (bf16)a1; o[2] = (bf16)a2; o[3] = (bf16)a3;
        *(bf16x4v*)&Sarr[(size_t)node * 256 + c] = o;
        if (lane == 0) deg[(rev ? NP : 0) + node] = kc2;
    }
}

// ---------------- fused node MLP (BK=32): Hid in LDS, out = Hid@Wt2^T + bn2 + NS ----------------
__global__ __launch_bounds__(256) void k_node(
    const bf16* __restrict__ S_to, const bf16* __restrict__ S_fr,
    const float* __restrict__ NS, const bf16* __restrict__ Wth,
    const bf16* __restrict__ Wt2,
    const float* __restrict__ u, const float* __restrict__ ru,
    const float* __restrict__ bn1, const float* __restrict__ bn2,
    const int* __restrict__ deg, float* __restrict__ out, int NP, int N) {
    __shared__ __align__(16) unsigned char smem[33792];   // max(As+Bs=25600, Hs=33792)
    bf16 (*As)[40]  = (bf16(*)[40])smem;                  // [64][40]
    bf16 (*Bs)[40]  = (bf16(*)[40])(smem + 5120);         // [256][40]
    bf16 (*Hs)[264] = (bf16(*)[264])smem;                 // [64][264]
    const int tid = threadIdx.x;
    const int wv = tid >> 6, lane = tid & 63;
    const int l15 = lane & 15, quad = lane >> 4;
    const int row0 = blockIdx.x * 64;
    const int srow = tid >> 2, kc = (tid & 3) * 8;
    floatx4 acc[4][4] = {};   // [colstrip][rowtile]; wave covers cols wv*64..+64
    const int arow = row0 + srow;
    for (int k0 = 0; k0 < 640; k0 += 32) {
        bf16x8 av;
        if (k0 < 512) {
            const bf16* S = (k0 < 256) ? S_to : S_fr;
            av = *(const bf16x8*)&S[(size_t)arow * 256 + (k0 & 255) + kc];
        } else {
            av = ns8(NS, arow, (k0 - 512) + kc, N);
        }
        bf16x8 bv[4];
#pragma unroll
        for (int j = 0; j < 4; ++j)
            bv[j] = *(const bf16x8*)&Wth[(size_t)(srow + 64 * j) * 640 + k0 + kc];
        __syncthreads();
        *(bf16x8*)&As[srow][kc] = av;
#pragma unroll
        for (int j = 0; j < 4; ++j)
            *(bf16x8*)&Bs[srow + 64 * j][kc] = bv[j];
        __syncthreads();
#pragma unroll
        for (int s = 0; s < 4; ++s) {
            bf16x8 bfr = *(const bf16x8*)&Bs[wv * 64 + s * 16 + l15][quad * 8];
#pragma unroll
            for (int r = 0; r < 4; ++r) {
                bf16x8 afr = *(const bf16x8*)&As[r * 16 + l15][quad * 8];
                acc[s][r] = __builtin_amdgcn_mfma_f32_16x16x32_bf16(afr, bfr, acc[s][r], 0, 0, 0);
            }
        }
    }
    __syncthreads();   // all As/Bs reads done before Hs overwrite
    // epilogue 1: deg terms + bias + relu -> Hs
#pragma unroll
    for (int s = 0; s < 4; ++s) {
        int col = wv * 64 + s * 16 + l15;
        float uc = u[col], rc = ru[col], bc = bn1[col];
#pragma unroll
        for (int r = 0; r < 4; ++r)
#pragma unroll
            for (int i = 0; i < 4; ++i) {
                int row = r * 16 + quad * 4 + i;
                float v = acc[s][r][i] + (float)deg[row0 + row] * uc
                        + (float)deg[NP + row0 + row] * rc + bc;
                Hs[row][col] = (bf16)fmaxf(v, 0.f);
            }
    }
    __syncthreads();
    // phase 2: out[64x128]; wave covers cols wv*32..+32 (2 strips)
    floatx4 acc2[2][4] = {};
    for (int k0 = 0; k0 < HH; k0 += 32) {
        bf16x8 afr[4];
#pragma unroll
        for (int r = 0; r < 4; ++r)
            afr[r] = *(const bf16x8*)&Hs[r * 16 + l15][k0 + quad * 8];
#pragma unroll
        for (int s = 0; s < 2; ++s) {
            int col = wv * 32 + s * 16 + l15;
            bf16x8 bfr = *(const bf16x8*)&Wt2[(size_t)col * HH + k0 + quad * 8];
#pragma unroll
            for (int r = 0; r < 4; ++r)
                acc2[s][r] = __builtin_amdgcn_mfma_f32_16x16x32_bf16(afr[r], bfr, acc2[s][r], 0, 0, 0);
        }
    }
#pragma unroll
    for (int s = 0; s < 2; ++s) {
        int ocol = wv * 32 + s * 16 + l15;
        float bb = bn2[ocol];
#pragma unroll
        for (int r = 0; r < 4; ++r)
#pragma unroll
            for (int i = 0; i < 4; ++i) {
                int orow = row0 + r * 16 + quad * 4 + i;
                if (orow < N)
                    out[(size_t)orow * DD + ocol] = acc2[s][r][i] + bb + NS[(size_t)orow * DD + ocol];
            }
    }
}

extern "C" void kernel_launch(void* const* d_in, const int* in_sizes, int n_in,
                              void* d_out, int out_size, void* d_ws, size_t ws_size,
                              hipStream_t stream) {
    const float* NS   = (const float*)d_in[0];
    const float* ef   = (const float*)d_in[1];
    const int* from_idx = (const int*)d_in[2];
    const int* to_idx   = (const int*)d_in[3];
    const float* W1  = (const float*)d_in[4];
    const float* b1  = (const float*)d_in[5];
    const float* W2  = (const float*)d_in[6];
    const float* b2  = (const float*)d_in[7];
    const float* RW1 = (const float*)d_in[8];
    const float* Rb1 = (const float*)d_in[9];
    const float* RW2 = (const float*)d_in[10];
    const float* Rb2 = (const float*)d_in[11];
    const float* Wn1 = (const float*)d_in[12];
    const float* bn1 = (const float*)d_in[13];
    const float* Wn2 = (const float*)d_in[14];
    const float* bn2 = (const float*)d_in[15];

    const int N  = in_sizes[0] / DD;
    const int E  = in_sizes[2];
    const int NP = ((N + 63) / 64) * 64;
    const int MB = NP / 64;
    const int NBF = NP / 32;
    const int NBINS = 2 * NBF;
    const int BINB = (E + 2047) / 2048;
    const int FRONT = BINB + 769 + 64 * ((MB + 7) / 8);   // proj padded to x8 row-groups
    const int PREB = 512 + (NBINS + 255) / 256;

    char* base = (char*)d_ws;
    size_t off_b = 0;
    auto alloc = [&](size_t b) { size_t o = off_b; off_b += (b + 255) & ~(size_t)255; return o; };
    unsigned char* Pn = (unsigned char*)(base + alloc((size_t)NP * 512));
    bf16* Pf   = (bf16*)(base + alloc((size_t)NP * 512 * 2));
    bf16* S_to = (bf16*)(base + alloc((size_t)NP * 256 * 2));
    bf16* S_fr = (bf16*)(base + alloc((size_t)NP * 256 * 2));
    int* deg   = (int*)(base + alloc((size_t)2 * NP * 4));
    int* gcur  = (int*)(base + alloc((size_t)NBINS * 4));
    int2* binbuf = (int2*)(base + alloc((size_t)NBINS * CAPB * 8));
    bf16* Wt1 = (bf16*)(base + alloc(1024 * 128 * 2));
    bf16* Wth = (bf16*)(base + alloc(256 * 640 * 2));
    bf16* Wt2 = (bf16*)(base + alloc(128 * 256 * 2));
    float* u  = (float*)(base + alloc(256 * 4));
    float* ru = (float*)(base + alloc(256 * 4));

    k_pre<<<PREB, 256, 0, stream>>>(W1, RW1, Wt1, gcur, NBINS);
    k_front<<<FRONT, 256, 0, stream>>>(NS, from_idx, to_idx, ef,
                                       W2, RW2, Wn1, Wn2, b2, Rb2, Wt1,
                                       gcur, binbuf, Pn, Pf, Wth, Wt2, u, ru,
                                       E, N, NP, NBINS, BINB, MB);
    k_aggf<<<NBINS, 256, 0, stream>>>(Pn, Pf, binbuf, gcur, W1, b1, RW1, Rb1,
                                      S_to, S_fr, deg, NP);
    k_node<<<MB, 256, 0, stream>>>(S_to, S_fr, NS, Wth, Wt2, u, ru, bn1, bn2,
                                   deg, (float*)d_out, NP, N);
}